// Round 25
// baseline (342.812 us; speedup 1.0000x reference)
//
#include <hip/hip_runtime.h>
#include <hip/hip_bf16.h>

typedef unsigned short u16;
typedef unsigned int u32;
typedef __bf16 bf16x8 __attribute__((ext_vector_type(8)));
typedef float f32x4 __attribute__((ext_vector_type(4)));
typedef unsigned short u16x8 __attribute__((ext_vector_type(8)));

#define S_ 2048
#define H_ 32
#define KV_ 8
#define D_ 128
#define HID_ 4096
#define KVD_ 1024
#define QKVN 6144
#define SINK_ 128
#define WIN_ 1024
#define POOL_ 100
#define KVB 64
#define QB 128
#define ATTNB ((S_ / QB) * H_)   // 512 attention blocks

__device__ __forceinline__ u16 f2bf(float f) {
  union { float f; u32 u; } v; v.f = f;
  u32 r = v.u + 0x7FFFu + ((v.u >> 16) & 1u);
  return (u16)(r >> 16);
}
__device__ __forceinline__ float bf2f(u16 h) {
  union { u32 u; float f; } v; v.u = ((u32)h) << 16;
  return v.f;
}
// async global->LDS, 16B per lane. LDS dest is wave-uniform base; HW writes base + lane*16.
__device__ __forceinline__ void glds16(const void* g, void* l) {
  __builtin_amdgcn_global_load_lds((__attribute__((address_space(1))) void*)g,
                                   (__attribute__((address_space(3))) void*)l, 16, 0, 0);
}

// ---------------- 64x64 transpose-convert helper, 256-thread version ----------------
__device__ __forceinline__ void tr64(const float* __restrict__ W, u16* __restrict__ Wt,
                                     int K, int N, int nt, int kt, int tid, u16 T[64][66]) {
  const int r = tid >> 4, c4 = tid & 15;
#pragma unroll
  for (int p = 0; p < 4; ++p) {
    int row = p * 16 + r;
    float4 v = *(const float4*)&W[(size_t)(kt * 64 + row) * N + nt * 64 + c4 * 4];
    T[row][c4 * 4 + 0] = f2bf(v.x);
    T[row][c4 * 4 + 1] = f2bf(v.y);
    T[row][c4 * 4 + 2] = f2bf(v.z);
    T[row][c4 * 4 + 3] = f2bf(v.w);
  }
  __syncthreads();
  const int n = tid >> 3, c8 = tid & 7;
#pragma unroll
  for (int p = 0; p < 2; ++p) {
    int row = p * 32 + n;
    u16x8 o;
#pragma unroll
    for (int i = 0; i < 8; ++i) o[i] = T[c8 * 8 + i][row];
    *(u16x8*)&Wt[(size_t)(nt * 64 + row) * K + kt * 64 + c8 * 8] = o;
  }
}

// ---------------- 64x64 transpose-convert helper, 512-thread version (for k_attn tail) ----------------
__device__ __forceinline__ void tr64w(const float* __restrict__ W, u16* __restrict__ Wt,
                                      int K, int N, int nt, int kt, int tid, u16 T[64][66]) {
  const int r = tid >> 4, c4 = tid & 15;   // r: 0..31
#pragma unroll
  for (int p = 0; p < 2; ++p) {
    int row = p * 32 + r;
    float4 v = *(const float4*)&W[(size_t)(kt * 64 + row) * N + nt * 64 + c4 * 4];
    T[row][c4 * 4 + 0] = f2bf(v.x);
    T[row][c4 * 4 + 1] = f2bf(v.y);
    T[row][c4 * 4 + 2] = f2bf(v.z);
    T[row][c4 * 4 + 3] = f2bf(v.w);
  }
  __syncthreads();
  const int n = tid >> 3, c8 = tid & 7;    // n: 0..63
  u16x8 o;
#pragma unroll
  for (int i = 0; i < 8; ++i) o[i] = T[c8 * 8 + i][n];
  *(u16x8*)&Wt[(size_t)(nt * 64 + n) * K + kt * 64 + c8 * 8] = o;
}

// ---------------- fused prep: hs convert + Wq/Wk/Wv transposes + rope tables ----------------
__global__ __launch_bounds__(256) void k_prep(const float* __restrict__ hs, u16* __restrict__ hsb,
                                              const float* __restrict__ Wq, const float* __restrict__ Wk,
                                              const float* __restrict__ Wv,
                                              u16* __restrict__ wqkv,
                                              float* __restrict__ cosT, float* __restrict__ sinT) {
  __shared__ u16 T[64][66];
  const int b = blockIdx.x, tid = threadIdx.x;
  if (b < 8192) {
    int i = b * 256 + tid;
    float4 v = ((const float4*)hs)[i];
    union { u16 s[4]; unsigned long long ll; } o;
    o.s[0] = f2bf(v.x); o.s[1] = f2bf(v.y); o.s[2] = f2bf(v.z); o.s[3] = f2bf(v.w);
    ((unsigned long long*)hsb)[i] = o.ll;
  } else if (b < 12288) {
    int id = b - 8192;
    tr64(Wq, wqkv, HID_, HID_, id % 64, id / 64, tid, T);
  } else if (b < 13312) {
    int id = b - 12288;
    tr64(Wk, wqkv + (size_t)4096 * HID_, HID_, KVD_, id % 16, id / 16, tid, T);
  } else if (b < 14336) {
    int id = b - 13312;
    tr64(Wv, wqkv + (size_t)5120 * HID_, HID_, KVD_, id % 16, id / 16, tid, T);
  } else {
    int idx = (b - 14336) * 256 + tid;
    int s = idx >> 6, i = idx & 63;
    float inv = powf(10000.f, -(float)i * (1.f / 64.f));
    float ang = (float)s * inv;
    cosT[idx] = cosf(ang);
    sinT[idx] = sinf(ang);
  }
}

// ---------------- fused positional: rope_q (in-place) + rope_k (relayout) + transpose_v ----------------
__global__ __launch_bounds__(256) void k_pos(u16* __restrict__ qkv, u16* __restrict__ kro,
                                             u16* __restrict__ vt,
                                             const float* __restrict__ cosT, const float* __restrict__ sinT) {
  __shared__ u16 T[32][33];
  const int b = blockIdx.x, tid = threadIdx.x;
  if (b < 16384) {
    int idx = b * 256 + tid;
    int i = idx & 63, h = (idx >> 6) & 31, s = idx >> 11;
    size_t base = (size_t)s * QKVN + h * D_ + i;
    float x1 = bf2f(qkv[base]), x2 = bf2f(qkv[base + 64]);
    float cs = cosT[(s << 6) + i], sn = sinT[(s << 6) + i];
    qkv[base] = f2bf(x1 * cs - x2 * sn);
    qkv[base + 64] = f2bf(x2 * cs + x1 * sn);
  } else if (b < 20480) {
    int idx = (b - 16384) * 256 + tid;
    int i = idx & 63, kv = (idx >> 6) & 7, s = idx >> 9;
    float x1 = bf2f(qkv[(size_t)s * QKVN + 4096 + kv * D_ + i]);
    float x2 = bf2f(qkv[(size_t)s * QKVN + 4096 + kv * D_ + i + 64]);
    float cs = cosT[(s << 6) + i], sn = sinT[(s << 6) + i];
    size_t ob = (size_t)kv * S_ * D_ + (size_t)s * D_ + i;
    kro[ob] = f2bf(x1 * cs - x2 * sn);
    kro[ob + 64] = f2bf(x2 * cs + x1 * sn);
  } else {
    int id = b - 20480;
    int st = id & 63, dt = (id >> 6) & 3, kv = id >> 8;
    int c = tid & 31, r0 = tid >> 5;
#pragma unroll
    for (int p = 0; p < 4; ++p) {
      int r = r0 + p * 8;
      T[r][c] = qkv[(size_t)(st * 32 + r) * QKVN + 5120 + kv * D_ + dt * 32 + c];
    }
    __syncthreads();
#pragma unroll
    for (int p = 0; p < 4; ++p) {
      int r = r0 + p * 8;
      vt[(size_t)kv * D_ * S_ + (size_t)(dt * 32 + r) * S_ + st * 32 + c] = T[c][r];
    }
  }
}

// ---------------- pooled feature ----------------
__global__ void k_feat(const u16* __restrict__ q, float* __restrict__ feat) {
  int d = blockIdx.x, tid = threadIdx.x;
  float p = 0.f;
  for (int idx = tid; idx < 2 * POOL_ * H_; idx += 256) {
    int pos = idx >> 5, hh = idx & 31;
    int s = pos < POOL_ ? pos : (S_ - 2 * POOL_) + pos;
    p += bf2f(q[(size_t)s * QKVN + hh * D_ + d]);
  }
#pragma unroll
  for (int m = 1; m < 64; m <<= 1) p += __shfl_xor(p, m);
  __shared__ float red[4];
  if ((tid & 63) == 0) red[tid >> 6] = p;
  __syncthreads();
  if (tid == 0) feat[d] = (red[0] + red[1] + red[2] + red[3]) * (1.f / (2 * POOL_ * H_));
}

// ---------------- router MLP, parallelized + load-pipelined ----------------
__global__ __launch_bounds__(256) void k_r1(const float* __restrict__ feat, const float* __restrict__ w,
                                            const float* __restrict__ b, float* __restrict__ h1) {
  __shared__ float fs[128];
  int tid = threadIdx.x;
  if (tid < 128) fs[tid] = feat[tid];
  __syncthreads();
  int o = blockIdx.x * 256 + tid;
  float a = b[o];
#pragma unroll 16
  for (int kk = 0; kk < 128; ++kk) a += fs[kk] * w[kk * 1024 + o];
  h1[o] = a / (1.f + expf(-a));
}
__global__ __launch_bounds__(256) void k_r2(const float* __restrict__ h1, const float* __restrict__ w,
                                            float* __restrict__ h2p) {
  __shared__ float hs[64];
  int tid = threadIdx.x, b = blockIdx.x;
  if (tid < 64) hs[tid] = h1[b * 64 + tid];
  __syncthreads();
  const float* wb = w + (size_t)b * 64 * 256 + tid;
  float p = 0.f;
#pragma unroll 16
  for (int kk = 0; kk < 64; ++kk) p += hs[kk] * wb[(size_t)kk * 256];
  h2p[b * 256 + tid] = p;
}
__global__ __launch_bounds__(256) void k_r3(const float* __restrict__ h2p, const float* __restrict__ b2,
                                            const float* __restrict__ w, const float* __restrict__ b3,
                                            float* __restrict__ h3) {
  __shared__ float h2s[256];
  int tid = threadIdx.x;
  float s = b2[tid];
#pragma unroll
  for (int j = 0; j < 16; ++j) s += h2p[j * 256 + tid];
  h2s[tid] = s;
  __syncthreads();
  int o = blockIdx.x * 256 + tid;
  float a = b3[o];
#pragma unroll 16
  for (int kk = 0; kk < 256; ++kk) a += h2s[kk] * w[kk * 512 + o];
  h3[o] = a / (1.f + expf(-a));
}
__global__ __launch_bounds__(256) void k_r45(const float* __restrict__ h3, const float* __restrict__ w4,
                                             const float* __restrict__ b4, const float* __restrict__ w5,
                                             const float* __restrict__ b5, const float* __restrict__ noise,
                                             float* __restrict__ mix) {
  __shared__ float h3s[512];
  __shared__ float hp[256];
  int tid = threadIdx.x;
  h3s[tid] = h3[tid];
  h3s[tid + 256] = h3[tid + 256];
  __syncthreads();
  int t = tid & 127, half = tid >> 7;
  float a = half ? 0.f : b4[t];
  const float* wcol = w4 + (size_t)(half << 8) * 128 + t;
  const float* hbase = h3s + (half << 8);
#pragma unroll 16
  for (int i = 0; i < 256; ++i) a += hbase[i] * wcol[(size_t)i * 128];
  hp[tid] = a;
  __syncthreads();
  if (tid < 128) {
    float v = hp[tid] + hp[tid + 128];
    float h4 = v / (1.f + expf(-v));
    hp[tid] = h4 * w5[tid];
  }
  __syncthreads();
  if (tid < 64) {
    float s = hp[tid] + hp[tid + 64];
#pragma unroll
    for (int m = 32; m >= 1; m >>= 1) s += __shfl_down(s, m);
    if (tid == 0) {
      float logits = s + b5[0];
      float u = noise[0];
      float g = -logf(-logf(u + 1e-8f) + 1e-8f);
      float zs = 1.f / (1.f + expf(-(logits + g)));
      mix[0] = zs > 0.5f ? 1.f : 0.f;
    }
  }
}

// ============ deep-pipelined GEMM, free-running body + earliest-issue staging ============
// Per-tile issue count == U for both instantiations (U=8: boundary 4 + ph0 2 + ph1 2;
// U=6: boundary 3 + ph0 2 + ph1 1), so the counted vmcnt(BS) retires exactly t+1's loads.
template <int MFRAG, int NFRAG>
__device__ __forceinline__ void stage_u(const u16* __restrict__ A, const u16* __restrict__ Bt,
                                        u16* buf, int m0, int n0, int K, int kg, int unit, int tid) {
  constexpr int AU = MFRAG / 2;
  constexpr int BM = MFRAG * 32;
  if (unit < AU) {
    int cell = unit * 512 + tid;
    int row = cell >> 3, c = cell & 7;
    glds16(A + (size_t)(m0 + row) * K + kg + ((c ^ (row & 7)) * 8),
           buf + ((size_t)(unit * 512 + (tid & ~63))) * 8);
  } else {
    int cell = (unit - AU) * 512 + tid;
    int row = cell >> 3, c = cell & 7;
    glds16(Bt + (size_t)(n0 + row) * K + kg + ((c ^ (row & 7)) * 8),
           buf + (size_t)BM * 64 + ((size_t)((unit - AU) * 512 + (tid & ~63))) * 8);
  }
}

template <int MFRAG, int NFRAG, int OUTF32>
__global__ __launch_bounds__(512, 1) void gemm_dp(const u16* __restrict__ A, const u16* __restrict__ Bt,
                                                  void* __restrict__ C, int M, int N, int K, int NTN) {
  constexpr int BM = MFRAG * 32;
  constexpr int BN = NFRAG * 64;
  constexpr int NH = NFRAG / 2;
  constexpr int U = MFRAG / 2 + NFRAG;
  static_assert(U == 8 || U == 6, "stage schedule assumes 6 or 8 units");
  constexpr int BS = (U == 8) ? 4 : 3;   // units issued at the boundary
  constexpr int TE = (BM + BN) * 64;
  __shared__ __align__(16) u16 lds[2 * TE];
  const int tid = threadIdx.x, w = tid >> 6, ln = tid & 63;
  const int lr = ln & 15, lk = ln >> 4;
  const int wr = w >> 2, wc = w & 3;
  const int nwg = gridDim.x, cpx = nwg >> 3;
  const int wg = (blockIdx.x & 7) * cpx + (blockIdx.x >> 3);
  const int m0 = (wg / NTN) * BM, n0 = (wg % NTN) * BN;
  f32x4 acc[MFRAG][NFRAG];
#pragma unroll
  for (int i = 0; i < MFRAG; ++i)
#pragma unroll
    for (int j = 0; j < NFRAG; ++j) acc[i][j] = (f32x4){0.f, 0.f, 0.f, 0.f};
  const int nt = K / 64;

  auto ldA = [&](const u16* buf, bf16x8* af, int kh) {
#pragma unroll
    for (int mf = 0; mf < MFRAG; ++mf) {
      int row = wr * (MFRAG * 16) + mf * 16 + lr;
      af[mf] = *(const bf16x8*)&buf[row * 64 + (((kh * 4 + lk) ^ (row & 7)) * 8)];
    }
  };
  auto ldB = [&](const u16* buf, bf16x8* bp, int kh, int nh) {
#pragma unroll
    for (int nf = 0; nf < NH; ++nf) {
      int brow = wc * (NFRAG * 16) + (nh * NH + nf) * 16 + lr;
      bp[nf] = *(const bf16x8*)&buf[BM * 64 + brow * 64 + (((kh * 4 + lk) ^ (brow & 7)) * 8)];
    }
  };
  auto MMA = [&](const bf16x8* af, const bf16x8* bp, int nh) {
    __builtin_amdgcn_s_setprio(1);
#pragma unroll
    for (int mf = 0; mf < MFRAG; ++mf)
#pragma unroll
      for (int nf = 0; nf < NH; ++nf)
        acc[mf][nh * NH + nf] =
            __builtin_amdgcn_mfma_f32_16x16x32_bf16(af[mf], bp[nf], acc[mf][nh * NH + nf], 0, 0, 0);
    __builtin_amdgcn_s_setprio(0);
  };
  auto wait_bs = [&]() {
    if constexpr (U == 8) asm volatile("s_waitcnt vmcnt(4)" ::: "memory");
    else asm volatile("s_waitcnt vmcnt(3)" ::: "memory");
  };

  // prologue: tile 0 fully + tile 1's boundary units; wait tile 0; phase-0 frags
#pragma unroll
  for (int i = 0; i < U; ++i) stage_u<MFRAG, NFRAG>(A, Bt, lds, m0, n0, K, 0, i, tid);
#pragma unroll
  for (int i = 0; i < BS; ++i) stage_u<MFRAG, NFRAG>(A, Bt, lds + TE, m0, n0, K, 64, i, tid);
  wait_bs();
  asm volatile("s_barrier" ::: "memory");
  bf16x8 afA[MFRAG], afB[MFRAG], b0[NH], b1[NH];
  ldA(lds, afA, 0);
  ldB(lds, b0, 0, 0);

  for (int t = 0; t < nt; ++t) {
    const u16* cb = lds + (t & 1) * TE;
    u16* nb = lds + ((t + 1) & 1) * TE;
    const bool hn = (t + 1 < nt);
    const int kn = (t + 1) * 64;
    // ---- free-running tile body: 4 MFMA clusters; remaining stage units issued early ----
    MMA(afA, b0, 0);
    ldB(cb, b1, 0, 1);
    if (hn) {
      stage_u<MFRAG, NFRAG>(A, Bt, nb, m0, n0, K, kn, BS, tid);
      stage_u<MFRAG, NFRAG>(A, Bt, nb, m0, n0, K, kn, BS + 1, tid);
    }
    MMA(afA, b1, 1);
    ldA(cb, afB, 1);
    ldB(cb, b0, 1, 0);
    if (hn) {
      if (U == 8) {
        stage_u<MFRAG, NFRAG>(A, Bt, nb, m0, n0, K, kn, 6, tid);
        stage_u<MFRAG, NFRAG>(A, Bt, nb, m0, n0, K, kn, 7, tid);
      } else {
        stage_u<MFRAG, NFRAG>(A, Bt, nb, m0, n0, K, kn, 5, tid);
      }
    }
    MMA(afB, b0, 0);
    ldB(cb, b1, 1, 1);
    MMA(afB, b1, 1);
    // ---- boundary ----
    asm volatile("s_barrier" ::: "memory");  // E: all waves' cb reads consumed before re-stage
    if (hn) {
      if (t + 2 < nt) {
#pragma unroll
        for (int i = 0; i < BS; ++i)
          stage_u<MFRAG, NFRAG>(A, Bt, (u16*)cb, m0, n0, K, (t + 2) * 64, i, tid);
        wait_bs();                                       // t+1 resident; t+2's BS in flight
      } else {
        asm volatile("s_waitcnt vmcnt(0)" ::: "memory"); // final drain
      }
      asm volatile("s_barrier" ::: "memory");  // F: t+1 resident for all waves
      ldA(nb, afA, 0);
      ldB(nb, b0, 0, 0);
    }
  }
  // epilogue
#pragma unroll
  for (int mf = 0; mf < MFRAG; ++mf) {
    int row = m0 + wr * (MFRAG * 16) + mf * 16 + lk * 4;
#pragma unroll
    for (int nf = 0; nf < NFRAG; ++nf) {
      int col = n0 + wc * (NFRAG * 16) + nf * 16 + lr;
#pragma unroll
      for (int jj = 0; jj < 4; ++jj) {
        float v = acc[mf][nf][jj];
        if (OUTF32) ((float*)C)[(size_t)(row + jj) * N + col] = v;
        else ((u16*)C)[(size_t)(row + jj) * N + col] = f2bf(v);
      }
    }
  }
}

// ---------------- fused attention + Wo-transpose tail; single barrier per tile ----------------
__global__ __launch_bounds__(512) void k_attn(const u16* __restrict__ q, const u16* __restrict__ kr,
                                              const u16* __restrict__ vt, u16* __restrict__ o,
                                              const float* __restrict__ mixp, int qs,
                                              const float* __restrict__ Wo, u16* __restrict__ wot) {
  __shared__ __align__(16) u16 Ks[2][KVB * 128];   // (kpos, d) swizzled
  __shared__ __align__(16) u16 Vs[2][128 * KVB];   // (d, kpos) swizzled
  __shared__ __align__(16) u16 Ps[8][16 * KVB];    // per-wave (q, kpos) swizzled
  const int tid = threadIdx.x, w = tid >> 6, ln = tid & 63;
  const int bid = blockIdx.x;
  if (bid >= ATTNB) {
    int id = bid - ATTNB;
    tr64w(Wo, wot, HID_, HID_, id & 63, id >> 6, tid, (u16(*)[66])(&Ks[0][0]));
    return;
  }
  const int lr = ln & 15, lk = ln >> 4;
  const int qblk = (S_ / QB - 1) - (bid >> 5);     // longest blocks dispatch first
  const int h = bid & 31, kv = h >> 2;
  const bool strm = (*mixp) > 0.5f;
  const int q0 = qblk * QB;
  const int qrow = q0 + w * 16 + lr;
  bf16x8 qf[4];
#pragma unroll
  for (int c = 0; c < 4; ++c)
    qf[c] = *(const bf16x8*)(q + (size_t)qrow * qs + h * D_ + c * 32 + lk * 8);
  f32x4 oacc[8];
#pragma unroll
  for (int c = 0; c < 8; ++c) oacc[c] = (f32x4){0.f, 0.f, 0.f, 0.f};
  float mrun[4], lsum[4];
#pragma unroll
  for (int j = 0; j < 4; ++j) { mrun[j] = -1e30f; lsum[j] = 0.f; }
  const u16* kbase = kr + (size_t)kv * S_ * D_;
  const u16* vbase = vt + (size_t)kv * D_ * S_;
  const int qg0 = q0 + w * 16 + lk * 4;
  const float scale = 0.08838834764831845f;
  const int ntl = 2 * qblk + 2;

  auto stage = [&](int kt, int b) {
    const int kb0 = kt * KVB;
#pragma unroll
    for (int c = 0; c < 2; ++c) {
      int r0 = c * 32 + w * 4;
      int rg = r0 + (ln >> 4);
      int cg = (ln & 15) ^ (rg & 7);
      glds16(kbase + (size_t)(kb0 + rg) * D_ + cg * 8, &Ks[b][r0 * 128]);
    }
#pragma unroll
    for (int c = 0; c < 2; ++c) {
      int r0 = c * 64 + w * 8;
      int rg = r0 + (ln >> 3);
      int cg = (ln & 7) ^ (rg & 7);
      glds16(vbase + (size_t)rg * S_ + kb0 + cg * 8, &Vs[b][r0 * KVB]);
    }
  };
  auto nxt = [&](int k) {
    ++k;
    if (strm)
      while (k < ntl && k * KVB >= SINK_ && k * KVB + KVB - 1 + WIN_ <= q0) ++k;
    return k;
  };

  int kt = 0, buf = 0;
  stage(0, 0);
  int ktn = nxt(0);
  while (kt < ntl) {
    const bool hn = (ktn < ntl);
    // single sync point: own loads of tile t done, then publish across waves.
    asm volatile("s_waitcnt vmcnt(0)" ::: "memory");
    asm volatile("s_barrier" ::: "memory");
    // prefetch t+1 into the other buffer (its tenant's reads finished before the barrier)
    if (hn) stage(ktn, buf ^ 1);
    const int kb0 = kt * KVB;
    const u16* ks = Ks[buf];
    const u16* vs = Vs[buf];
    f32x4 sg[4];
#pragma unroll
    for (int g = 0; g < 4; ++g) sg[g] = (f32x4){0.f, 0.f, 0.f, 0.f};
    __builtin_amdgcn_s_setprio(1);
#pragma unroll
    for (int g = 0; g < 4; ++g) {
      int krow = g * 16 + lr;
      int sw = krow & 7;
#pragma unroll
      for (int c = 0; c < 4; ++c) {
        bf16x8 kf = *(const bf16x8*)&ks[krow * 128 + (((c * 4 + lk) ^ sw) * 8)];
        sg[g] = __builtin_amdgcn_mfma_f32_16x16x32_bf16(qf[c], kf, sg[g], 0, 0, 0);
      }
    }
    __builtin_amdgcn_s_setprio(0);
    const bool diag = (kt >= 2 * qblk);              // last two tiles cross the causal diagonal
    const bool needm = diag ||
        (strm && !(kb0 + KVB <= SINK_ || kb0 >= q0 + QB - WIN_));
    if (needm) {
#pragma unroll
      for (int g = 0; g < 4; ++g) {
        int kg = kb0 + g * 16 + lr;
#pragma unroll
        for (int j = 0; j < 4; ++j) {
          int qi = qg0 + j;
          float v = sg[g][j] * scale;
          bool ok = (kg <= qi) && (!strm || kg < SINK_ || kg > qi - WIN_);
          sg[g][j] = ok ? v : -1e30f;
        }
      }
    } else {
#pragma unroll
      for (int g = 0; g < 4; ++g)
#pragma unroll
        for (int j = 0; j < 4; ++j) sg[g][j] *= scale;
    }
    // per-lane defer-max check: row-max<=mrun+8 is implied by all lanes' local max<=mrun+8
    float dmax = -1e30f;
#pragma unroll
    for (int j = 0; j < 4; ++j) {
      float pm = fmaxf(fmaxf(sg[0][j], sg[1][j]), fmaxf(sg[2][j], sg[3][j]));
      dmax = fmaxf(dmax, pm - mrun[j]);
    }
    if (!__all(dmax <= 8.f)) {
      // rescale path (rare): full row-max tree, update mrun, scale lsum/oacc per-lane
      float rmax[4];
#pragma unroll
      for (int j = 0; j < 4; ++j)
        rmax[j] = fmaxf(fmaxf(sg[0][j], sg[1][j]), fmaxf(sg[2][j], sg[3][j]));
#pragma unroll
      for (int m2 = 1; m2 < 16; m2 <<= 1)
#pragma unroll
        for (int j = 0; j < 4; ++j) rmax[j] = fmaxf(rmax[j], __shfl_xor(rmax[j], m2));
      float corr[4];
#pragma unroll
      for (int j = 0; j < 4; ++j) {
        float mn = fmaxf(mrun[j], rmax[j]);
        corr[j] = __expf(mrun[j] - mn);
        mrun[j] = mn;
        lsum[j] *= corr[j];
      }
#pragma unroll
      for (int c = 0; c < 8; ++c) {
        f32x4 t2 = oacc[c];
        t2[0] *= corr[0]; t2[1] *= corr[1]; t2[2] *= corr[2]; t2[3] *= corr[3];
        oacc[c] = t2;
      }
    }
    // exp + per-lane partial sums (reduced once in epilogue)
#pragma unroll
    for (int g = 0; g < 4; ++g)
#pragma unroll
      for (int j = 0; j < 4; ++j) {
        float p = __expf(sg[g][j] - mrun[j]);
        sg[g][j] = p;
        lsum[j] += p;
      }
#pragma unroll
    for (int g = 0; g < 4; ++g) {
      int col = g * 16 + lr;
      int c16 = col >> 3;
#pragma unroll
      for (int j = 0; j < 4; ++j) {
        int row = lk * 4 + j;
        Ps[w][row * KVB + ((c16 ^ (row & 7)) * 8) + (col & 7)] = f2bf(sg[g][j]);
      }
    }
    __builtin_amdgcn_s_setprio(1);
#pragma unroll
    for (int half = 0; half < 2; ++half) {
      bf16x8 pf = *(const bf16x8*)&Ps[w][lr * KVB + (((half * 4 + lk) ^ (lr & 7)) * 8)];
#pragma unroll
      for (int cc = 0; cc < 8; ++cc) {
        int vrow = cc * 16 + lr;
        bf16x8 vf = *(const bf16x8*)&vs[vrow * KVB + (((half * 4 + lk) ^ (vrow & 7)) * 8)];
        oacc[cc] = __builtin_amdgcn_mfma_f32_16x16x32_bf16(pf, vf, oacc[cc], 0, 0, 0);
      }
    }
    __builtin_amdgcn_s_setprio(0);
    kt = ktn;
    ktn = nxt(ktn);
    buf ^= 1;
  }
  // epilogue: single row-sum reduction (16 lanes sharing a row group)
#pragma unroll
  for (int m2 = 1; m2 < 16; m2 <<= 1)
#pragma unroll
    for (int j = 0; j < 4; ++j) lsum[j] += __shfl_xor(lsum[j], m2);
#pragma unroll
  for (int cc = 0; cc < 8; ++cc)
#pragma unroll
    for (int j = 0; j < 4; ++j) {
      float ov = oacc[cc][j] / lsum[j];
      o[(size_t)(qg0 + j) * HID_ + h * D_ + cc * 16 + lr] = f2bf(ov);
    }
}

extern "C" void kernel_launch(void* const* d_in, const int* in_sizes, int n_in,
                              void* d_out, int out_size, void* d_ws, size_t ws_size,
                              hipStream_t stream) {
  const float* hs = (const float*)d_in[0];
  const float* Wq = (const float*)d_in[1];
  const float* Wk = (const float*)d_in[2];
  const float* Wv = (const float*)d_in[3];
  const float* Wo = (const float*)d_in[4];
  const float* fe1_w = (const float*)d_in[5];
  const float* fe1_b = (const float*)d_in[6];
  const float* fe2_w = (const float*)d_in[7];
  const float* fe2_b = (const float*)d_in[8];
  const float* r1_w = (const float*)d_in[9];
  const float* r1_b = (const float*)d_in[10];
  const float* r2_w = (const float*)d_in[11];
  const float* r2_b = (const float*)d_in[12];
  const float* r3_w = (const float*)d_in[13];
  const float* r3_b = (const float*)d_in[14];
  const float* noise = (const float*)d_in[15];

  char* ws = (char*)d_ws;
  size_t off = 0;
  auto alloc = [&](size_t b) { char* p = ws + off; off += (b + 255) & ~(size_t)255; return p; };
  u16* hsb = (u16*)alloc((size_t)S_ * HID_ * 2);
  u16* wqkv = (u16*)alloc((size_t)QKVN * HID_ * 2);   // [Wq^T; Wk^T; Wv^T]
  u16* qkvbuf = (u16*)alloc((size_t)S_ * QKVN * 2);   // cols: q | k | v
  u16* wot = (u16*)alloc((size_t)HID_ * HID_ * 2);    // Wo^T (written by k_attn tail blocks)
  u16* krbuf = (u16*)alloc((size_t)S_ * KVD_ * 2);
  u16* vtbuf = (u16*)alloc((size_t)S_ * KVD_ * 2);
  u16* obuf = (u16*)alloc((size_t)S_ * HID_ * 2);
  float* cosT = (float*)alloc((size_t)S_ * 64 * 4);
  float* sinT = (float*)alloc((size_t)S_ * 64 * 4);
  float* feat = (float*)alloc(512);
  float* mix = (float*)alloc(256);
  float* h1buf = (float*)alloc(1024 * 4);
  float* h2p = (float*)alloc(16 * 256 * 4);
  float* h3buf = (float*)alloc(512 * 4);

  // fused prep: convert + Wq/Wk/Wv transposes + rope tables (Wo^T moved to k_attn tail)
  k_prep<<<dim3(14848), dim3(256), 0, stream>>>(hs, hsb, Wq, Wk, Wv, wqkv, cosT, sinT);

  // fused QKV GEMM: 128x384 tile -> grid 16x16 = 256 blocks (full CU fill)
  gemm_dp<4, 6, 0><<<dim3(256), dim3(512), 0, stream>>>(hsb, wqkv, (void*)qkvbuf,
                                                        S_, QKVN, HID_, QKVN / 384);

  // fused positional: rope_q + rope_k + transpose_v (one dispatch)
  k_pos<<<dim3(22528), dim3(256), 0, stream>>>(qkvbuf, krbuf, vtbuf, cosT, sinT);

  // router: feat -> parallel 4-kernel MLP chain
  k_feat<<<dim3(D_), dim3(256), 0, stream>>>(qkvbuf, feat);
  k_r1<<<dim3(4), dim3(256), 0, stream>>>(feat, fe1_w, fe1_b, h1buf);
  k_r2<<<dim3(16), dim3(256), 0, stream>>>(h1buf, fe2_w, h2p);
  k_r3<<<dim3(2), dim3(256), 0, stream>>>(h2p, fe2_b, r1_w, r1_b, h3buf);
  k_r45<<<dim3(1), dim3(256), 0, stream>>>(h3buf, r2_w, r2_b, r3_w, r3_b, noise, mix);

  // fused attention (512 blocks) + Wo^T transpose tail (4096 blocks)
  k_attn<<<dim3(ATTNB + 4096), dim3(512), 0, stream>>>(qkvbuf, krbuf, vtbuf, obuf, mix, QKVN,
                                                       Wo, wot);

  // Wo GEMM: 128x256 tile -> grid 16x16 = 256 blocks (full fill), fp32 direct to d_out
  gemm_dp<4, 4, 1><<<dim3(256), dim3(512), 0, stream>>>(obuf, wot, d_out,
                                                        S_, HID_, HID_, HID_ / 256);
}

// Round 26
// 338.908 us; speedup vs baseline: 1.0115x; 1.0115x over previous
//
#include <hip/hip_runtime.h>
#include <hip/hip_bf16.h>

typedef unsigned short u16;
typedef unsigned int u32;
typedef __bf16 bf16x8 __attribute__((ext_vector_type(8)));
typedef float f32x4 __attribute__((ext_vector_type(4)));
typedef unsigned short u16x8 __attribute__((ext_vector_type(8)));

#define S_ 2048
#define H_ 32
#define KV_ 8
#define D_ 128
#define HID_ 4096
#define KVD_ 1024
#define QKVN 6144
#define SINK_ 128
#define WIN_ 1024
#define POOL_ 100
#define KVB 64
#define QB 128
#define ATTNB ((S_ / QB) * H_)   // 512 attention blocks

__device__ __forceinline__ u16 f2bf(float f) {
  union { float f; u32 u; } v; v.f = f;
  u32 r = v.u + 0x7FFFu + ((v.u >> 16) & 1u);
  return (u16)(r >> 16);
}
__device__ __forceinline__ float bf2f(u16 h) {
  union { u32 u; float f; } v; v.u = ((u32)h) << 16;
  return v.f;
}
// async global->LDS, 16B per lane. LDS dest is wave-uniform base; HW writes base + lane*16.
__device__ __forceinline__ void glds16(const void* g, void* l) {
  __builtin_amdgcn_global_load_lds((__attribute__((address_space(1))) void*)g,
                                   (__attribute__((address_space(3))) void*)l, 16, 0, 0);
}

// ---------------- 64x64 transpose-convert helper, 256-thread version ----------------
__device__ __forceinline__ void tr64(const float* __restrict__ W, u16* __restrict__ Wt,
                                     int K, int N, int nt, int kt, int tid, u16 T[64][66]) {
  const int r = tid >> 4, c4 = tid & 15;
#pragma unroll
  for (int p = 0; p < 4; ++p) {
    int row = p * 16 + r;
    float4 v = *(const float4*)&W[(size_t)(kt * 64 + row) * N + nt * 64 + c4 * 4];
    T[row][c4 * 4 + 0] = f2bf(v.x);
    T[row][c4 * 4 + 1] = f2bf(v.y);
    T[row][c4 * 4 + 2] = f2bf(v.z);
    T[row][c4 * 4 + 3] = f2bf(v.w);
  }
  __syncthreads();
  const int n = tid >> 3, c8 = tid & 7;
#pragma unroll
  for (int p = 0; p < 2; ++p) {
    int row = p * 32 + n;
    u16x8 o;
#pragma unroll
    for (int i = 0; i < 8; ++i) o[i] = T[c8 * 8 + i][row];
    *(u16x8*)&Wt[(size_t)(nt * 64 + row) * K + kt * 64 + c8 * 8] = o;
  }
}

// ---------------- 64x64 transpose-convert helper, 512-thread version (for k_attn tail) ----------------
__device__ __forceinline__ void tr64w(const float* __restrict__ W, u16* __restrict__ Wt,
                                      int K, int N, int nt, int kt, int tid, u16 T[64][66]) {
  const int r = tid >> 4, c4 = tid & 15;   // r: 0..31
#pragma unroll
  for (int p = 0; p < 2; ++p) {
    int row = p * 32 + r;
    float4 v = *(const float4*)&W[(size_t)(kt * 64 + row) * N + nt * 64 + c4 * 4];
    T[row][c4 * 4 + 0] = f2bf(v.x);
    T[row][c4 * 4 + 1] = f2bf(v.y);
    T[row][c4 * 4 + 2] = f2bf(v.z);
    T[row][c4 * 4 + 3] = f2bf(v.w);
  }
  __syncthreads();
  const int n = tid >> 3, c8 = tid & 7;    // n: 0..63
  u16x8 o;
#pragma unroll
  for (int i = 0; i < 8; ++i) o[i] = T[c8 * 8 + i][n];
  *(u16x8*)&Wt[(size_t)(nt * 64 + n) * K + kt * 64 + c8 * 8] = o;
}

// ---------------- fused prep: hs convert + Wq/Wk/Wv transposes + rope tables ----------------
__global__ __launch_bounds__(256) void k_prep(const float* __restrict__ hs, u16* __restrict__ hsb,
                                              const float* __restrict__ Wq, const float* __restrict__ Wk,
                                              const float* __restrict__ Wv,
                                              u16* __restrict__ wqkv,
                                              float* __restrict__ cosT, float* __restrict__ sinT) {
  __shared__ u16 T[64][66];
  const int b = blockIdx.x, tid = threadIdx.x;
  if (b < 8192) {
    int i = b * 256 + tid;
    float4 v = ((const float4*)hs)[i];
    union { u16 s[4]; unsigned long long ll; } o;
    o.s[0] = f2bf(v.x); o.s[1] = f2bf(v.y); o.s[2] = f2bf(v.z); o.s[3] = f2bf(v.w);
    ((unsigned long long*)hsb)[i] = o.ll;
  } else if (b < 12288) {
    int id = b - 8192;
    tr64(Wq, wqkv, HID_, HID_, id % 64, id / 64, tid, T);
  } else if (b < 13312) {
    int id = b - 12288;
    tr64(Wk, wqkv + (size_t)4096 * HID_, HID_, KVD_, id % 16, id / 16, tid, T);
  } else if (b < 14336) {
    int id = b - 13312;
    tr64(Wv, wqkv + (size_t)5120 * HID_, HID_, KVD_, id % 16, id / 16, tid, T);
  } else {
    int idx = (b - 14336) * 256 + tid;
    int s = idx >> 6, i = idx & 63;
    float inv = powf(10000.f, -(float)i * (1.f / 64.f));
    float ang = (float)s * inv;
    cosT[idx] = cosf(ang);
    sinT[idx] = sinf(ang);
  }
}

// ---------------- fused positional: rope_q (in-place) + rope_k (relayout) + transpose_v ----------------
__global__ __launch_bounds__(256) void k_pos(u16* __restrict__ qkv, u16* __restrict__ kro,
                                             u16* __restrict__ vt,
                                             const float* __restrict__ cosT, const float* __restrict__ sinT) {
  __shared__ u16 T[32][33];
  const int b = blockIdx.x, tid = threadIdx.x;
  if (b < 16384) {
    int idx = b * 256 + tid;
    int i = idx & 63, h = (idx >> 6) & 31, s = idx >> 11;
    size_t base = (size_t)s * QKVN + h * D_ + i;
    float x1 = bf2f(qkv[base]), x2 = bf2f(qkv[base + 64]);
    float cs = cosT[(s << 6) + i], sn = sinT[(s << 6) + i];
    qkv[base] = f2bf(x1 * cs - x2 * sn);
    qkv[base + 64] = f2bf(x2 * cs + x1 * sn);
  } else if (b < 20480) {
    int idx = (b - 16384) * 256 + tid;
    int i = idx & 63, kv = (idx >> 6) & 7, s = idx >> 9;
    float x1 = bf2f(qkv[(size_t)s * QKVN + 4096 + kv * D_ + i]);
    float x2 = bf2f(qkv[(size_t)s * QKVN + 4096 + kv * D_ + i + 64]);
    float cs = cosT[(s << 6) + i], sn = sinT[(s << 6) + i];
    size_t ob = (size_t)kv * S_ * D_ + (size_t)s * D_ + i;
    kro[ob] = f2bf(x1 * cs - x2 * sn);
    kro[ob + 64] = f2bf(x2 * cs + x1 * sn);
  } else {
    int id = b - 20480;
    int st = id & 63, dt = (id >> 6) & 3, kv = id >> 8;
    int c = tid & 31, r0 = tid >> 5;
#pragma unroll
    for (int p = 0; p < 4; ++p) {
      int r = r0 + p * 8;
      T[r][c] = qkv[(size_t)(st * 32 + r) * QKVN + 5120 + kv * D_ + dt * 32 + c];
    }
    __syncthreads();
#pragma unroll
    for (int p = 0; p < 4; ++p) {
      int r = r0 + p * 8;
      vt[(size_t)kv * D_ * S_ + (size_t)(dt * 32 + r) * S_ + st * 32 + c] = T[c][r];
    }
  }
}

// ---------------- pooled feature ----------------
__global__ void k_feat(const u16* __restrict__ q, float* __restrict__ feat) {
  int d = blockIdx.x, tid = threadIdx.x;
  float p = 0.f;
  for (int idx = tid; idx < 2 * POOL_ * H_; idx += 256) {
    int pos = idx >> 5, hh = idx & 31;
    int s = pos < POOL_ ? pos : (S_ - 2 * POOL_) + pos;
    p += bf2f(q[(size_t)s * QKVN + hh * D_ + d]);
  }
#pragma unroll
  for (int m = 1; m < 64; m <<= 1) p += __shfl_xor(p, m);
  __shared__ float red[4];
  if ((tid & 63) == 0) red[tid >> 6] = p;
  __syncthreads();
  if (tid == 0) feat[d] = (red[0] + red[1] + red[2] + red[3]) * (1.f / (2 * POOL_ * H_));
}

// ---------------- router MLP, parallelized + load-pipelined ----------------
__global__ __launch_bounds__(256) void k_r1(const float* __restrict__ feat, const float* __restrict__ w,
                                            const float* __restrict__ b, float* __restrict__ h1) {
  __shared__ float fs[128];
  int tid = threadIdx.x;
  if (tid < 128) fs[tid] = feat[tid];
  __syncthreads();
  int o = blockIdx.x * 256 + tid;
  float a = b[o];
#pragma unroll 16
  for (int kk = 0; kk < 128; ++kk) a += fs[kk] * w[kk * 1024 + o];
  h1[o] = a / (1.f + expf(-a));
}
__global__ __launch_bounds__(256) void k_r2(const float* __restrict__ h1, const float* __restrict__ w,
                                            float* __restrict__ h2p) {
  __shared__ float hs[64];
  int tid = threadIdx.x, b = blockIdx.x;
  if (tid < 64) hs[tid] = h1[b * 64 + tid];
  __syncthreads();
  const float* wb = w + (size_t)b * 64 * 256 + tid;
  float p = 0.f;
#pragma unroll 16
  for (int kk = 0; kk < 64; ++kk) p += hs[kk] * wb[(size_t)kk * 256];
  h2p[b * 256 + tid] = p;
}
__global__ __launch_bounds__(256) void k_r3(const float* __restrict__ h2p, const float* __restrict__ b2,
                                            const float* __restrict__ w, const float* __restrict__ b3,
                                            float* __restrict__ h3) {
  __shared__ float h2s[256];
  int tid = threadIdx.x;
  float s = b2[tid];
#pragma unroll
  for (int j = 0; j < 16; ++j) s += h2p[j * 256 + tid];
  h2s[tid] = s;
  __syncthreads();
  int o = blockIdx.x * 256 + tid;
  float a = b3[o];
#pragma unroll 16
  for (int kk = 0; kk < 256; ++kk) a += h2s[kk] * w[kk * 512 + o];
  h3[o] = a / (1.f + expf(-a));
}
__global__ __launch_bounds__(256) void k_r45(const float* __restrict__ h3, const float* __restrict__ w4,
                                             const float* __restrict__ b4, const float* __restrict__ w5,
                                             const float* __restrict__ b5, const float* __restrict__ noise,
                                             float* __restrict__ mix) {
  __shared__ float h3s[512];
  __shared__ float hp[256];
  int tid = threadIdx.x;
  h3s[tid] = h3[tid];
  h3s[tid + 256] = h3[tid + 256];
  __syncthreads();
  int t = tid & 127, half = tid >> 7;
  float a = half ? 0.f : b4[t];
  const float* wcol = w4 + (size_t)(half << 8) * 128 + t;
  const float* hbase = h3s + (half << 8);
#pragma unroll 16
  for (int i = 0; i < 256; ++i) a += hbase[i] * wcol[(size_t)i * 128];
  hp[tid] = a;
  __syncthreads();
  if (tid < 128) {
    float v = hp[tid] + hp[tid + 128];
    float h4 = v / (1.f + expf(-v));
    hp[tid] = h4 * w5[tid];
  }
  __syncthreads();
  if (tid < 64) {
    float s = hp[tid] + hp[tid + 64];
#pragma unroll
    for (int m = 32; m >= 1; m >>= 1) s += __shfl_down(s, m);
    if (tid == 0) {
      float logits = s + b5[0];
      float u = noise[0];
      float g = -logf(-logf(u + 1e-8f) + 1e-8f);
      float zs = 1.f / (1.f + expf(-(logits + g)));
      mix[0] = zs > 0.5f ? 1.f : 0.f;
    }
  }
}

// ============ deep-pipelined GEMM, free-running tile body (round-18/22 verified best) ============
template <int MFRAG, int NFRAG>
__device__ __forceinline__ void stage_u(const u16* __restrict__ A, const u16* __restrict__ Bt,
                                        u16* buf, int m0, int n0, int K, int kg, int unit, int tid) {
  constexpr int AU = MFRAG / 2;
  constexpr int BM = MFRAG * 32;
  if (unit < AU) {
    int cell = unit * 512 + tid;
    int row = cell >> 3, c = cell & 7;
    glds16(A + (size_t)(m0 + row) * K + kg + ((c ^ (row & 7)) * 8),
           buf + ((size_t)(unit * 512 + (tid & ~63))) * 8);
  } else {
    int cell = (unit - AU) * 512 + tid;
    int row = cell >> 3, c = cell & 7;
    glds16(Bt + (size_t)(n0 + row) * K + kg + ((c ^ (row & 7)) * 8),
           buf + (size_t)BM * 64 + ((size_t)((unit - AU) * 512 + (tid & ~63))) * 8);
  }
}

template <int MFRAG, int NFRAG, int OUTF32>
__global__ __launch_bounds__(512, 1) void gemm_dp(const u16* __restrict__ A, const u16* __restrict__ Bt,
                                                  void* __restrict__ C, int M, int N, int K, int NTN) {
  constexpr int BM = MFRAG * 32;
  constexpr int BN = NFRAG * 64;
  constexpr int NH = NFRAG / 2;
  constexpr int U = MFRAG / 2 + NFRAG;
  static_assert(U == 8 || U == 6, "stage schedule assumes 6 or 8 units");
  constexpr int TE = (BM + BN) * 64;
  __shared__ __align__(16) u16 lds[2 * TE];
  const int tid = threadIdx.x, w = tid >> 6, ln = tid & 63;
  const int lr = ln & 15, lk = ln >> 4;
  const int wr = w >> 2, wc = w & 3;
  const int nwg = gridDim.x, cpx = nwg >> 3;
  const int wg = (blockIdx.x & 7) * cpx + (blockIdx.x >> 3);
  const int m0 = (wg / NTN) * BM, n0 = (wg % NTN) * BN;
  f32x4 acc[MFRAG][NFRAG];
#pragma unroll
  for (int i = 0; i < MFRAG; ++i)
#pragma unroll
    for (int j = 0; j < NFRAG; ++j) acc[i][j] = (f32x4){0.f, 0.f, 0.f, 0.f};
  const int nt = K / 64;

  auto ldA = [&](const u16* buf, bf16x8* af, int kh) {
#pragma unroll
    for (int mf = 0; mf < MFRAG; ++mf) {
      int row = wr * (MFRAG * 16) + mf * 16 + lr;
      af[mf] = *(const bf16x8*)&buf[row * 64 + (((kh * 4 + lk) ^ (row & 7)) * 8)];
    }
  };
  auto ldB = [&](const u16* buf, bf16x8* bp, int kh, int nh) {
#pragma unroll
    for (int nf = 0; nf < NH; ++nf) {
      int brow = wc * (NFRAG * 16) + (nh * NH + nf) * 16 + lr;
      bp[nf] = *(const bf16x8*)&buf[BM * 64 + brow * 64 + (((kh * 4 + lk) ^ (brow & 7)) * 8)];
    }
  };
  auto MMA = [&](const bf16x8* af, const bf16x8* bp, int nh) {
    __builtin_amdgcn_s_setprio(1);
#pragma unroll
    for (int mf = 0; mf < MFRAG; ++mf)
#pragma unroll
      for (int nf = 0; nf < NH; ++nf)
        acc[mf][nh * NH + nf] =
            __builtin_amdgcn_mfma_f32_16x16x32_bf16(af[mf], bp[nf], acc[mf][nh * NH + nf], 0, 0, 0);
    __builtin_amdgcn_s_setprio(0);
  };

  // prologue: tile 0 fully + units 0,1 of tile 1; then phase-0 fragment reads
#pragma unroll
  for (int i = 0; i < U; ++i) stage_u<MFRAG, NFRAG>(A, Bt, lds, m0, n0, K, 0, i, tid);
  stage_u<MFRAG, NFRAG>(A, Bt, lds + TE, m0, n0, K, 64, 0, tid);
  stage_u<MFRAG, NFRAG>(A, Bt, lds + TE, m0, n0, K, 64, 1, tid);
  asm volatile("s_waitcnt vmcnt(2)" ::: "memory");
  asm volatile("s_barrier" ::: "memory");
  bf16x8 afA[MFRAG], afB[MFRAG], b0[NH], b1[NH];
  ldA(lds, afA, 0);
  ldB(lds, b0, 0, 0);

  for (int t = 0; t < nt; ++t) {
    const u16* cb = lds + (t & 1) * TE;
    u16* nb = lds + ((t + 1) & 1) * TE;
    const bool hn = (t + 1 < nt);
    const int kn = (t + 1) * 64;
    // ---- free-running tile body: 4 MFMA clusters, shadows interleaved, no barriers ----
    MMA(afA, b0, 0);
    ldB(cb, b1, 0, 1);
    if (hn) {
      stage_u<MFRAG, NFRAG>(A, Bt, nb, m0, n0, K, kn, 2, tid);
      stage_u<MFRAG, NFRAG>(A, Bt, nb, m0, n0, K, kn, 3, tid);
    }
    MMA(afA, b1, 1);
    ldA(cb, afB, 1);
    ldB(cb, b0, 1, 0);
    if (hn) {
      stage_u<MFRAG, NFRAG>(A, Bt, nb, m0, n0, K, kn, 4, tid);
      stage_u<MFRAG, NFRAG>(A, Bt, nb, m0, n0, K, kn, 5, tid);
    }
    MMA(afB, b0, 0);
    ldB(cb, b1, 1, 1);
    if (hn && U == 8) {
      stage_u<MFRAG, NFRAG>(A, Bt, nb, m0, n0, K, kn, 6, tid);
      stage_u<MFRAG, NFRAG>(A, Bt, nb, m0, n0, K, kn, 7, tid);
    }
    MMA(afB, b1, 1);
    // ---- boundary ----
    asm volatile("s_barrier" ::: "memory");  // E: all waves' cb reads consumed before re-stage
    if (hn) {
      if (t + 2 < nt) {
        stage_u<MFRAG, NFRAG>(A, Bt, (u16*)cb, m0, n0, K, (t + 2) * 64, 0, tid);
        stage_u<MFRAG, NFRAG>(A, Bt, (u16*)cb, m0, n0, K, (t + 2) * 64, 1, tid);
        asm volatile("s_waitcnt vmcnt(2)" ::: "memory");  // t+1 resident; t+2's 2 in flight
      } else {
        asm volatile("s_waitcnt vmcnt(0)" ::: "memory");  // final drain
      }
      asm volatile("s_barrier" ::: "memory");  // F: t+1 resident for all waves
      ldA(nb, afA, 0);
      ldB(nb, b0, 0, 0);
    }
  }
  // epilogue
#pragma unroll
  for (int mf = 0; mf < MFRAG; ++mf) {
    int row = m0 + wr * (MFRAG * 16) + mf * 16 + lk * 4;
#pragma unroll
    for (int nf = 0; nf < NFRAG; ++nf) {
      int col = n0 + wc * (NFRAG * 16) + nf * 16 + lr;
#pragma unroll
      for (int jj = 0; jj < 4; ++jj) {
        float v = acc[mf][nf][jj];
        if (OUTF32) ((float*)C)[(size_t)(row + jj) * N + col] = v;
        else ((u16*)C)[(size_t)(row + jj) * N + col] = f2bf(v);
      }
    }
  }
}

// ---------------- fused attention + Wo-transpose tail; single barrier per tile ----------------
__global__ __launch_bounds__(512) void k_attn(const u16* __restrict__ q, const u16* __restrict__ kr,
                                              const u16* __restrict__ vt, u16* __restrict__ o,
                                              const float* __restrict__ mixp, int qs,
                                              const float* __restrict__ Wo, u16* __restrict__ wot) {
  __shared__ __align__(16) u16 Ks[2][KVB * 128];   // (kpos, d) swizzled
  __shared__ __align__(16) u16 Vs[2][128 * KVB];   // (d, kpos) swizzled
  __shared__ __align__(16) u16 Ps[8][16 * KVB];    // per-wave (q, kpos) swizzled
  const int tid = threadIdx.x, w = tid >> 6, ln = tid & 63;
  const int bid = blockIdx.x;
  if (bid >= ATTNB) {
    int id = bid - ATTNB;
    tr64w(Wo, wot, HID_, HID_, id & 63, id >> 6, tid, (u16(*)[66])(&Ks[0][0]));
    return;
  }
  const int lr = ln & 15, lk = ln >> 4;
  const int qblk = (S_ / QB - 1) - (bid >> 5);     // longest blocks dispatch first
  const int h = bid & 31, kv = h >> 2;
  const bool strm = (*mixp) > 0.5f;
  const int q0 = qblk * QB;
  const int qrow = q0 + w * 16 + lr;
  bf16x8 qf[4];
#pragma unroll
  for (int c = 0; c < 4; ++c)
    qf[c] = *(const bf16x8*)(q + (size_t)qrow * qs + h * D_ + c * 32 + lk * 8);
  f32x4 oacc[8];
#pragma unroll
  for (int c = 0; c < 8; ++c) oacc[c] = (f32x4){0.f, 0.f, 0.f, 0.f};
  float mrun[4], lsum[4];
#pragma unroll
  for (int j = 0; j < 4; ++j) { mrun[j] = -1e30f; lsum[j] = 0.f; }
  const u16* kbase = kr + (size_t)kv * S_ * D_;
  const u16* vbase = vt + (size_t)kv * D_ * S_;
  const int qg0 = q0 + w * 16 + lk * 4;
  const float scale = 0.08838834764831845f;
  const int ntl = 2 * qblk + 2;

  auto stage = [&](int kt, int b) {
    const int kb0 = kt * KVB;
#pragma unroll
    for (int c = 0; c < 2; ++c) {
      int r0 = c * 32 + w * 4;
      int rg = r0 + (ln >> 4);
      int cg = (ln & 15) ^ (rg & 7);
      glds16(kbase + (size_t)(kb0 + rg) * D_ + cg * 8, &Ks[b][r0 * 128]);
    }
#pragma unroll
    for (int c = 0; c < 2; ++c) {
      int r0 = c * 64 + w * 8;
      int rg = r0 + (ln >> 3);
      int cg = (ln & 7) ^ (rg & 7);
      glds16(vbase + (size_t)rg * S_ + kb0 + cg * 8, &Vs[b][r0 * KVB]);
    }
  };
  auto nxt = [&](int k) {
    ++k;
    if (strm)
      while (k < ntl && k * KVB >= SINK_ && k * KVB + KVB - 1 + WIN_ <= q0) ++k;
    return k;
  };

  int kt = 0, buf = 0;
  stage(0, 0);
  int ktn = nxt(0);
  while (kt < ntl) {
    const bool hn = (ktn < ntl);
    // single sync point: own loads of tile t done, then publish across waves.
    asm volatile("s_waitcnt vmcnt(0)" ::: "memory");
    asm volatile("s_barrier" ::: "memory");
    // prefetch t+1 into the other buffer (its tenant's reads finished before the barrier)
    if (hn) stage(ktn, buf ^ 1);
    const int kb0 = kt * KVB;
    const u16* ks = Ks[buf];
    const u16* vs = Vs[buf];
    f32x4 sg[4];
#pragma unroll
    for (int g = 0; g < 4; ++g) sg[g] = (f32x4){0.f, 0.f, 0.f, 0.f};
    __builtin_amdgcn_s_setprio(1);
#pragma unroll
    for (int g = 0; g < 4; ++g) {
      int krow = g * 16 + lr;
      int sw = krow & 7;
#pragma unroll
      for (int c = 0; c < 4; ++c) {
        bf16x8 kf = *(const bf16x8*)&ks[krow * 128 + (((c * 4 + lk) ^ sw) * 8)];
        sg[g] = __builtin_amdgcn_mfma_f32_16x16x32_bf16(qf[c], kf, sg[g], 0, 0, 0);
      }
    }
    __builtin_amdgcn_s_setprio(0);
    const bool diag = (kt >= 2 * qblk);              // last two tiles cross the causal diagonal
    const bool needm = diag ||
        (strm && !(kb0 + KVB <= SINK_ || kb0 >= q0 + QB - WIN_));
    if (needm) {
#pragma unroll
      for (int g = 0; g < 4; ++g) {
        int kg = kb0 + g * 16 + lr;
#pragma unroll
        for (int j = 0; j < 4; ++j) {
          int qi = qg0 + j;
          float v = sg[g][j] * scale;
          bool ok = (kg <= qi) && (!strm || kg < SINK_ || kg > qi - WIN_);
          sg[g][j] = ok ? v : -1e30f;
        }
      }
    } else {
#pragma unroll
      for (int g = 0; g < 4; ++g)
#pragma unroll
        for (int j = 0; j < 4; ++j) sg[g][j] *= scale;
    }
    // per-lane defer-max check: row-max<=mrun+8 is implied by all lanes' local max<=mrun+8
    float dmax = -1e30f;
#pragma unroll
    for (int j = 0; j < 4; ++j) {
      float pm = fmaxf(fmaxf(sg[0][j], sg[1][j]), fmaxf(sg[2][j], sg[3][j]));
      dmax = fmaxf(dmax, pm - mrun[j]);
    }
    if (!__all(dmax <= 8.f)) {
      // rescale path (rare): full row-max tree, update mrun, scale lsum/oacc per-lane
      float rmax[4];
#pragma unroll
      for (int j = 0; j < 4; ++j)
        rmax[j] = fmaxf(fmaxf(sg[0][j], sg[1][j]), fmaxf(sg[2][j], sg[3][j]));
#pragma unroll
      for (int m2 = 1; m2 < 16; m2 <<= 1)
#pragma unroll
        for (int j = 0; j < 4; ++j) rmax[j] = fmaxf(rmax[j], __shfl_xor(rmax[j], m2));
      float corr[4];
#pragma unroll
      for (int j = 0; j < 4; ++j) {
        float mn = fmaxf(mrun[j], rmax[j]);
        corr[j] = __expf(mrun[j] - mn);
        mrun[j] = mn;
        lsum[j] *= corr[j];
      }
#pragma unroll
      for (int c = 0; c < 8; ++c) {
        f32x4 t2 = oacc[c];
        t2[0] *= corr[0]; t2[1] *= corr[1]; t2[2] *= corr[2]; t2[3] *= corr[3];
        oacc[c] = t2;
      }
    }
    // exp + per-lane partial sums (reduced once in epilogue)
#pragma unroll
    for (int g = 0; g < 4; ++g)
#pragma unroll
      for (int j = 0; j < 4; ++j) {
        float p = __expf(sg[g][j] - mrun[j]);
        sg[g][j] = p;
        lsum[j] += p;
      }
#pragma unroll
    for (int g = 0; g < 4; ++g) {
      int col = g * 16 + lr;
      int c16 = col >> 3;
#pragma unroll
      for (int j = 0; j < 4; ++j) {
        int row = lk * 4 + j;
        Ps[w][row * KVB + ((c16 ^ (row & 7)) * 8) + (col & 7)] = f2bf(sg[g][j]);
      }
    }
    __builtin_amdgcn_s_setprio(1);
#pragma unroll
    for (int half = 0; half < 2; ++half) {
      bf16x8 pf = *(const bf16x8*)&Ps[w][lr * KVB + (((half * 4 + lk) ^ (lr & 7)) * 8)];
#pragma unroll
      for (int cc = 0; cc < 8; ++cc) {
        int vrow = cc * 16 + lr;
        bf16x8 vf = *(const bf16x8*)&vs[vrow * KVB + (((half * 4 + lk) ^ (vrow & 7)) * 8)];
        oacc[cc] = __builtin_amdgcn_mfma_f32_16x16x32_bf16(pf, vf, oacc[cc], 0, 0, 0);
      }
    }
    __builtin_amdgcn_s_setprio(0);
    kt = ktn;
    ktn = nxt(ktn);
    buf ^= 1;
  }
  // epilogue: single row-sum reduction (16 lanes sharing a row group)
#pragma unroll
  for (int m2 = 1; m2 < 16; m2 <<= 1)
#pragma unroll
    for (int j = 0; j < 4; ++j) lsum[j] += __shfl_xor(lsum[j], m2);
#pragma unroll
  for (int cc = 0; cc < 8; ++cc)
#pragma unroll
    for (int j = 0; j < 4; ++j) {
      float ov = oacc[cc][j] / lsum[j];
      o[(size_t)(qg0 + j) * HID_ + h * D_ + cc * 16 + lr] = f2bf(ov);
    }
}

extern "C" void kernel_launch(void* const* d_in, const int* in_sizes, int n_in,
                              void* d_out, int out_size, void* d_ws, size_t ws_size,
                              hipStream_t stream) {
  const float* hs = (const float*)d_in[0];
  const float* Wq = (const float*)d_in[1];
  const float* Wk = (const float*)d_in[2];
  const float* Wv = (const float*)d_in[3];
  const float* Wo = (const float*)d_in[4];
  const float* fe1_w = (const float*)d_in[5];
  const float* fe1_b = (const float*)d_in[6];
  const float* fe2_w = (const float*)d_in[7];
  const float* fe2_b = (const float*)d_in[8];
  const float* r1_w = (const float*)d_in[9];
  const float* r1_b = (const float*)d_in[10];
  const float* r2_w = (const float*)d_in[11];
  const float* r2_b = (const float*)d_in[12];
  const float* r3_w = (const float*)d_in[13];
  const float* r3_b = (const float*)d_in[14];
  const float* noise = (const float*)d_in[15];

  char* ws = (char*)d_ws;
  size_t off = 0;
  auto alloc = [&](size_t b) { char* p = ws + off; off += (b + 255) & ~(size_t)255; return p; };
  u16* hsb = (u16*)alloc((size_t)S_ * HID_ * 2);
  u16* wqkv = (u16*)alloc((size_t)QKVN * HID_ * 2);   // [Wq^T; Wk^T; Wv^T]
  u16* qkvbuf = (u16*)alloc((size_t)S_ * QKVN * 2);   // cols: q | k | v
  u16* wot = (u16*)alloc((size_t)HID_ * HID_ * 2);    // Wo^T (written by k_attn tail blocks)
  u16* krbuf = (u16*)alloc((size_t)S_ * KVD_ * 2);
  u16* vtbuf = (u16*)alloc((size_t)S_ * KVD_ * 2);
  u16* obuf = (u16*)alloc((size_t)S_ * HID_ * 2);
  float* cosT = (float*)alloc((size_t)S_ * 64 * 4);
  float* sinT = (float*)alloc((size_t)S_ * 64 * 4);
  float* feat = (float*)alloc(512);
  float* mix = (float*)alloc(256);
  float* h1buf = (float*)alloc(1024 * 4);
  float* h2p = (float*)alloc(16 * 256 * 4);
  float* h3buf = (float*)alloc(512 * 4);

  // fused prep: convert + Wq/Wk/Wv transposes + rope tables (Wo^T moved to k_attn tail)
  k_prep<<<dim3(14848), dim3(256), 0, stream>>>(hs, hsb, Wq, Wk, Wv, wqkv, cosT, sinT);

  // fused QKV GEMM: 128x384 tile -> grid 16x16 = 256 blocks (full CU fill)
  gemm_dp<4, 6, 0><<<dim3(256), dim3(512), 0, stream>>>(hsb, wqkv, (void*)qkvbuf,
                                                        S_, QKVN, HID_, QKVN / 384);

  // fused positional: rope_q + rope_k + transpose_v (one dispatch)
  k_pos<<<dim3(22528), dim3(256), 0, stream>>>(qkvbuf, krbuf, vtbuf, cosT, sinT);

  // router: feat -> parallel 4-kernel MLP chain
  k_feat<<<dim3(D_), dim3(256), 0, stream>>>(qkvbuf, feat);
  k_r1<<<dim3(4), dim3(256), 0, stream>>>(feat, fe1_w, fe1_b, h1buf);
  k_r2<<<dim3(16), dim3(256), 0, stream>>>(h1buf, fe2_w, h2p);
  k_r3<<<dim3(2), dim3(256), 0, stream>>>(h2p, fe2_b, r1_w, r1_b, h3buf);
  k_r45<<<dim3(1), dim3(256), 0, stream>>>(h3buf, r2_w, r2_b, r3_w, r3_b, noise, mix);

  // fused attention (512 blocks) + Wo^T transpose tail (4096 blocks)
  k_attn<<<dim3(ATTNB + 4096), dim3(512), 0, stream>>>(qkvbuf, krbuf, vtbuf, obuf, mix, QKVN,
                                                       Wo, wot);

  // Wo GEMM: 128x256 tile -> grid 16x16 = 256 blocks (full fill), fp32 direct to d_out
  gemm_dp<4, 4, 1><<<dim3(256), dim3(512), 0, stream>>>(obuf, wot, d_out,
                                                        S_, HID_, HID_, HID_ / 256);
}